// Round 18
// baseline (199.904 us; speedup 1.0000x reference)
//
#include <hip/hip_runtime.h>

#define NNODES 100000
#define NEDGES 3200000
#define ETOT   (NEDGES + NNODES)
#define NEG_SLOPE 0.2f
#define LOG2E 1.4426950408889634f

#define NPB 64                               // nodes per bucket (dst >> 6)
#define NBUCK ((NNODES + NPB - 1) / NPB)     // 1563 buckets
#define NCHUNK 512                           // edge chunks (round-36: was 256)
#define CHUNK_E ((ETOT + NCHUNK - 1) / NCHUNK)  // 6446 edges/chunk
#define M2 (NBUCK * NCHUNK)                  // 800256 (chunk-scan length)
#define NSB2 (M2 / 512)                      // 1563 — scan block == bucket
#define FS_CAP 4096                          // fine_agg1 LDS staging capacity

// bf16 storage via raw ushort — no hip_fp16.h / hip_bf16.h dependency.
__device__ __forceinline__ unsigned short f2bf(float f) {
    unsigned u = __float_as_uint(f);
    u += 0x7FFFu + ((u >> 16) & 1u);         // round-to-nearest-even
    return (unsigned short)(u >> 16);
}

// edge e in [0, NEDGES): src = ei[e], dst = ei[NEDGES+e]
// edge e in [NEDGES, ETOT): self-loop, src = dst = e - NEDGES
__device__ __forceinline__ void edge_sd(int e, const int* __restrict__ ei, int& s, int& d) {
    if (e < NEDGES) { s = ei[e]; d = ei[NEDGES + e]; }
    else            { s = e - NEDGES; d = s; }
}

__device__ __forceinline__ float lrelu(float v) {
    return v > 0.0f ? v : NEG_SLOPE * v;
}

// Alpha tables pre-scaled by log2(e) (round-26): edge weight = single v_exp_f32.
__device__ __forceinline__ float edge_w(float z) {
    return __builtin_amdgcn_exp2f(lrelu(z));
}

// ---- cross-lane primitives ----
template<int CTRL>
__device__ __forceinline__ float dpp_mov(float v) {
    return __int_as_float(__builtin_amdgcn_mov_dpp(__float_as_int(v), CTRL, 0xF, 0xF, true));
}
template<int CTRL>
__device__ __forceinline__ float dpp_add(float v) { return v + dpp_mov<CTRL>(v); }
template<int IMM>
__device__ __forceinline__ float swz(float v) {
    return __int_as_float(__builtin_amdgcn_ds_swizzle(__float_as_int(v), IMM));
}
// Sum over all 16 lanes of each row (rotations 1,2,4,8).
__device__ __forceinline__ float row16_sum(float v) {
    v = dpp_add<0x121>(v);   // row_ror:1
    v = dpp_add<0x122>(v);   // row_ror:2
    v = dpp_add<0x124>(v);   // row_ror:4
    v = dpp_add<0x128>(v);   // row_ror:8
    return v;
}

// ---------------- deterministic chunked bucket sort ----------------

__global__ void chunk_hist(const int* __restrict__ ei, int* __restrict__ H) {
    __shared__ int h[NBUCK];
    int c = blockIdx.x;
    for (int i = threadIdx.x; i < NBUCK; i += blockDim.x) h[i] = 0;
    __syncthreads();
    int lo = c * CHUNK_E, hi = lo + CHUNK_E; if (hi > ETOT) hi = ETOT;
    for (int e = lo + threadIdx.x; e < hi; e += blockDim.x) {
        int d = (e < NEDGES) ? ei[NEDGES + e] : (e - NEDGES);
        atomicAdd(&h[d >> 6], 1);
    }
    __syncthreads();
    for (int i = threadIdx.x; i < NBUCK; i += blockDim.x) H[c * NBUCK + i] = h[i];
}

// Round-36: with NCHUNK=512, scan block == bucket (i = b*512 + c). Block blk
// scans bucket blk's 512 chunk-counts; bsum2[blk] = bucket total. prep merged
// in (block NSB2). cvec: [0,1]=c1s [2,3]=c1d [4..19]=c2s [20..35]=c2d
// (log2e-prescaled).
__global__ __launch_bounds__(512)
void cscan_local_prep(const int* __restrict__ H, int* __restrict__ off,
                      int* __restrict__ bsum2,
                      const float* __restrict__ W1, const float* __restrict__ as1,
                      const float* __restrict__ ad1, const float* __restrict__ W2,
                      const float* __restrict__ as2, const float* __restrict__ ad2,
                      float* __restrict__ cvec) {
    int blk = blockIdx.x, t = threadIdx.x;
    if (blk == NSB2) {                       // prep role
        if (t < 2) {
            float s = 0.f, d = 0.f;
            for (int f = 0; f < 16; ++f) { s += W1[t * 16 + f] * as1[f]; d += W1[t * 16 + f] * ad1[f]; }
            cvec[t] = s * LOG2E; cvec[2 + t] = d * LOG2E;
        }
        if (t < 16) {
            float s = 0.f, d = 0.f;
            for (int f = 0; f < 64; ++f) { s += W2[t * 64 + f] * as2[f]; d += W2[t * 64 + f] * ad2[f]; }
            cvec[4 + t] = s * LOG2E; cvec[20 + t] = d * LOG2E;
        }
        return;
    }
    __shared__ int arr[512];
    int v = H[t * NBUCK + blk];              // chunk t, bucket blk
    arr[t] = v;
    __syncthreads();
    for (int o = 1; o < 512; o <<= 1) {
        int u = (t >= o) ? arr[t - o] : 0;
        __syncthreads();
        arr[t] += u;
        __syncthreads();
    }
    off[blk * 512 + t] = arr[t] - v;         // exclusive, within bucket blk
    if (t == 511) bsum2[blk] = arr[t];
}

// Round-36: bsum scan over NSB2=1563 entries (2048-wide, 2 per thread) in
// block 0; blocks 1.. = alpha1 node records {x0,x1,as1,pad} (16B, one line).
__global__ __launch_bounds__(1024)
void cscan_bsum_alpha1(const int* __restrict__ bsum2, int* __restrict__ boff2,
                       const float* __restrict__ x, const float* __restrict__ cvec,
                       float4* __restrict__ nrec1, float* __restrict__ ad_) {
    int t = threadIdx.x;
    if (blockIdx.x == 0) {
        __shared__ int arr[2048];
        int i1 = t + 1024;
        int v0 = (t < NSB2) ? bsum2[t] : 0;
        int v1 = (i1 < NSB2) ? bsum2[i1] : 0;
        arr[t] = v0; arr[i1] = v1;
        __syncthreads();
        for (int o = 1; o < 2048; o <<= 1) {
            int u0 = (t >= o) ? arr[t - o] : 0;
            int u1 = (i1 >= o) ? arr[i1 - o] : 0;
            __syncthreads();
            arr[t] += u0; arr[i1] += u1;
            __syncthreads();
        }
        if (t < NSB2) boff2[t] = arr[t] - v0;
        if (i1 < NSB2) boff2[i1] = arr[i1] - v1;
        return;
    }
    int n = (blockIdx.x - 1) * 1024 + t;
    if (n >= NNODES) return;
    float2 xv = ((const float2*)x)[n];
    float as = xv.x * cvec[0] + xv.y * cvec[1];
    ad_[n] = xv.x * cvec[2] + xv.y * cvec[3];
    nrec1[n] = make_float4(xv.x, xv.y, as, 0.f);
}

// LDS-staged scatter (round-22 structure). Round-36: 512 chunks -> ~58KB LDS
// -> 2 blocks/CU (was 1 at 98KB); serial edge loop halves; offset fold is now
// boff2[b] (scan block == bucket).
__global__ __launch_bounds__(1024)
void chunk_scatter(const int* __restrict__ ei, const int* __restrict__ off,
                   const int* __restrict__ boff2, const int* __restrict__ H,
                   int* __restrict__ pairs) {
    __shared__ int plds[CHUNK_E];            // 25784 B: packed pair per local slot
    __shared__ unsigned short blds[CHUNK_E]; // 12892 B: bucket id per local slot
    __shared__ int sc[2048];                 //  8192 B: inclusive scan of counts
    __shared__ int lcur[NBUCK];              //  6252 B: local alloc cursor
    __shared__ int gbase[NBUCK];             //  6252 B: off_g[b,c] - lpref[b]
    int c = blockIdx.x, t = threadIdx.x;
    for (int b = t; b < 2048; b += 1024) sc[b] = (b < NBUCK) ? H[c * NBUCK + b] : 0;
    __syncthreads();
    for (int o = 1; o < 2048; o <<= 1) {
        int i1 = t + 1024;
        int v0 = (t >= o) ? sc[t - o] : 0;
        int v1 = (i1 >= o) ? sc[i1 - o] : 0;
        __syncthreads();
        sc[t] += v0; sc[i1] += v1;
        __syncthreads();
    }
    for (int b = t; b < NBUCK; b += 1024) {
        int excl = (b == 0) ? 0 : sc[b - 1];        // exclusive local prefix
        lcur[b]  = excl;
        gbase[b] = off[b * NCHUNK + c] + boff2[b] - excl;
    }
    __syncthreads();
    int lo = c * CHUNK_E, hi = lo + CHUNK_E; if (hi > ETOT) hi = ETOT;
    int n = hi - lo;
    for (int e = lo + t; e < hi; e += 1024) {
        int s, d; edge_sd(e, ei, s, d);
        int b = d >> 6;
        int slot = atomicAdd(&lcur[b], 1);
        plds[slot] = ((d & 63) << 17) | s;          // src < 2^17
        blds[slot] = (unsigned short)b;
    }
    __syncthreads();
    for (int i = t; i < n; i += 1024)
        pairs[gbase[blds[i]] + i] = plds[i];        // coalesced within segments
}

// ---------------- fused fine sort + layer-1 aggregation -----------------------
// Round-30 fusion; round-34 16-lane groups (plain loop — round-35 prefetch
// reverted, it was neutral-negative: loops are TLP-covered).
__global__ __launch_bounds__(512)
void fine_agg1(const int* __restrict__ off, const int* __restrict__ boff2,
               const int* __restrict__ pairs,
               const float4* __restrict__ nrec1, const float* __restrict__ ad_,
               const float* __restrict__ W1, const float* __restrict__ b1,
               const float* __restrict__ cvec,
               int* __restrict__ row_start, int* __restrict__ csr_src,
               float* __restrict__ nrec2, float* __restrict__ ad2_) {
    __shared__ int sp[FS_CAP];               // 16KB arrival-order pairs
    __shared__ int spc[FS_CAP];              // 16KB node-compacted src ids
    __shared__ int arr[NPB];
    __shared__ int cur[NPB];
    __shared__ int lstart[NPB + 1];
    int b = blockIdx.x;
    int t = threadIdx.x;
    int base = off[b * NCHUNK] + boff2[b];
    int bend = (b == NBUCK - 1) ? ETOT : off[(b + 1) * NCHUNK] + boff2[b + 1];
    int n = bend - base;
    if (t < NPB) arr[t] = 0;
    __syncthreads();
    bool fits = (n <= FS_CAP);
    if (fits) {
        for (int i = t; i < n; i += 512) {
            int p = pairs[base + i];
            sp[i] = p;
            atomicAdd(&arr[p >> 17], 1);
        }
    } else {
        for (int i = t; i < n; i += 512)
            atomicAdd(&arr[pairs[base + i] >> 17], 1);
    }
    __syncthreads();
    int v = (t < NPB) ? arr[t] : 0;
    __syncthreads();
    for (int o = 1; o < NPB; o <<= 1) {           // inclusive scan over 64 counts
        int u = (t < NPB && t >= o) ? arr[t - o] : 0;
        __syncthreads();
        if (t < NPB) arr[t] += u;
        __syncthreads();
    }
    if (t < NPB) {
        int node = b * NPB + t;
        int start = base + arr[t] - v;            // exclusive prefix
        cur[t] = start;
        lstart[t] = start;
        if (node < NNODES) row_start[node] = start;
    }
    if (t == 0) lstart[NPB] = bend;
    if (b == NBUCK - 1 && t == 0) row_start[NNODES] = ETOT;
    __syncthreads();
    if (fits) {
        for (int i = t; i < n; i += 512) {
            int p = sp[i];
            int slot = atomicAdd(&cur[p >> 17], 1);
            int src = p & 0x1FFFF;
            csr_src[slot] = src;
            spc[slot - base] = src;               // LDS copy for fused agg
        }
    } else {
        for (int i = t; i < n; i += 512) {
            int p = pairs[base + i];
            int slot = atomicAdd(&cur[p >> 17], 1);
            csr_src[slot] = p & 0x1FFFF;
        }
        __threadfence_block();
    }
    __syncthreads();
    // ---- fused agg_l1: 8 waves x 4 quads = 32 nodes per pass, 2 passes ----
    int wave = t >> 6;
    int quad = (t >> 4) & 3;
    int l16  = t & 15;
#pragma unroll
    for (int pass = 0; pass < 2; ++pass) {
        int ln = pass * 32 + wave * 4 + quad;     // 0..63, uniform per 16-lane group
        int node = b * NPB + ln;
        if (node >= NNODES) continue;             // uniform branch per group
        int nbase = lstart[ln], nend = lstart[ln + 1];
        float adv = ad_[node];
        float a0 = 0.f, a1 = 0.f, ss = 0.f;
        if (fits) {
            for (int i = nbase + l16; i < nend; i += 16) {
                int sj = spc[i - base];
                float4 r = nrec1[sj];             // ONE 16B gather: x0,x1,as1
                float w = edge_w(r.z + adv);
                ss += w; a0 += w * r.x; a1 += w * r.y;
            }
        } else {
            for (int i = nbase + l16; i < nend; i += 16) {
                int sj = csr_src[i];
                float4 r = nrec1[sj];
                float w = edge_w(r.z + adv);
                ss += w; a0 += w * r.x; a1 += w * r.y;
            }
        }
        a0 = row16_sum(a0); a1 = row16_sum(a1); ss = row16_sum(ss);
        int f = l16;                              // each lane owns one feature
        float vv = (a0 * W1[f] + a1 * W1[16 + f]) / ss + b1[f];
        float vr = vv > 0.f ? vv : 0.f;
        unsigned short* grow = (unsigned short*)(nrec2 + (size_t)node * 16);
        grow[l16] = f2bf(vr);                     // bf16 g row, bytes 0..31
        // fused alpha2 (f32): row-local 16-feature sums
        float s2 = vr * cvec[4 + f];
        float d2 = vr * cvec[20 + f];
        s2 = row16_sum(s2); d2 = row16_sum(d2);
        if (l16 == 0) {
            nrec2[(size_t)node * 16 + 8] = s2;    // as2 at bytes 32..35 (same line)
            ad2_[node] = d2;
        }
    }
}

// ---------------- layer 2: aggregate bf16 g, @W2 in epilogue ------------------
// Four nodes per wave, 16 lanes each (round-34); one 64B record line per edge
// (round-27); transposed butterfly completes within the 16-lane row (plain
// loop — round-35 prefetch reverted).
__global__ void agg_l2(const int* __restrict__ row_start, const int* __restrict__ csr_src,
                       const float* __restrict__ nrec2, const float* __restrict__ ad_,
                       const float* __restrict__ W2, const float* __restrict__ b2,
                       float* __restrict__ out) {
    __shared__ float tot[4][4][16];
    int wave = threadIdx.x >> 6;
    int quad = (threadIdx.x >> 4) & 3;
    int l16  = threadIdx.x & 15;
    int node = blockIdx.x * 16 + wave * 4 + quad;  // exact grid: NNODES/16 blocks
    int base = row_start[node], end = row_start[node + 1];
    float adv = ad_[node];
    float acc[16];
#pragma unroll
    for (int k = 0; k < 16; ++k) acc[k] = 0.f;
    float ss = 0.f;
    for (int i = base + l16; i < end; i += 16) {
        int sj = csr_src[i];                        // coalesced within group
        const float* recf = nrec2 + (size_t)sj * 16;
        const uint4* rec4 = (const uint4*)recf;
        uint4 u0 = rec4[0], u1 = rec4[1];           // g row bf16x16 (32B)
        float as2v = recf[8];                       // as2 (same 64B line)
        float w = edge_w(as2v + adv);
        ss += w;
        unsigned uu[8] = {u0.x, u0.y, u0.z, u0.w, u1.x, u1.y, u1.z, u1.w};
#pragma unroll
        for (int j = 0; j < 8; ++j) {
            acc[2 * j]     += w * __uint_as_float(uu[j] << 16);
            acc[2 * j + 1] += w * __uint_as_float(uu[j] & 0xFFFF0000u);
        }
    }
    // ---- transposed butterfly within the 16-lane row: lane l16 -> feature l16
#pragma unroll
    for (int j = 0; j < 8; ++j) {
        float keep = (l16 & 1) ? acc[2 * j + 1] : acc[2 * j];
        float send = (l16 & 1) ? acc[2 * j]     : acc[2 * j + 1];
        acc[j] = keep + dpp_mov<0xB1>(send);
    }
#pragma unroll
    for (int j = 0; j < 4; ++j) {
        float keep = (l16 & 2) ? acc[2 * j + 1] : acc[2 * j];
        float send = (l16 & 2) ? acc[2 * j]     : acc[2 * j + 1];
        acc[j] = keep + dpp_mov<0x4E>(send);
    }
#pragma unroll
    for (int j = 0; j < 2; ++j) {
        float keep = (l16 & 4) ? acc[2 * j + 1] : acc[2 * j];
        float send = (l16 & 4) ? acc[2 * j]     : acc[2 * j + 1];
        acc[j] = keep + swz<0x101F>(send);
    }
    float r;
    {
        float keep = (l16 & 8) ? acc[1] : acc[0];
        float send = (l16 & 8) ? acc[0] : acc[1];
        r = keep + swz<0x201F>(send);
    }
    // r is the complete per-node total of feature l16 (no swz16 needed).
    float st = row16_sum(ss);
    tot[wave][quad][l16] = r;                      // in-order wave-local LDS
    float inv = 1.0f / st;
#pragma unroll
    for (int j = 0; j < 4; ++j) {
        float o = 0.f;
#pragma unroll
        for (int k = 0; k < 16; ++k)
            o += tot[wave][quad][k] * W2[k * 64 + j * 16 + l16];  // 64B/group
        o = o * inv + b2[j * 16 + l16];
        float rv = o > 0.f ? o : 0.f;
        out[(size_t)node * 64 + j * 16 + l16] = rv;
    }
}

extern "C" void kernel_launch(void* const* d_in, const int* in_sizes, int n_in,
                              void* d_out, int out_size, void* d_ws, size_t ws_size,
                              hipStream_t stream) {
    const float* x     = (const float*)d_in[0];
    const int*   ei    = (const int*)  d_in[1];
    const float* W1    = (const float*)d_in[2];
    const float* as1w  = (const float*)d_in[3];
    const float* ad1w  = (const float*)d_in[4];
    const float* b1    = (const float*)d_in[5];
    const float* W2    = (const float*)d_in[6];
    const float* as2w  = (const float*)d_in[7];
    const float* ad2w  = (const float*)d_in[8];
    const float* b2    = (const float*)d_in[9];
    float* out = (float*)d_out;

    // ws layout (4-byte elems, 38.8 MB total — unchanged from proven):
    //   row_start[N+4] | csr_src[ETOT] | nrec2/H shared slot (6.4MB: H 3.2MB
    //   dead after chunk_scatter, nrec2 first written by fine_agg1) | adb[N] |
    //   ad2b[N] | cvec[64] | pairs[ETOT] | off[M2] | bsum2[2048] | boff2[2048]
    //   | nrec1[N float4]
    int* row_start = (int*)d_ws;
    int* csr_src   = row_start + (NNODES + 4);
    float* nrec2   = (float*)(csr_src + ETOT);   // 6.4MB slot, doubles as H
    int* H         = (int*)nrec2;                // M2 ints = 3.2MB <= slot
    float* adb     = nrec2 + (size_t)NNODES * 16;
    float* ad2b    = adb + NNODES;
    float* cvec    = ad2b + NNODES;              // 36 floats used
    int* pairs     = (int*)(cvec + 64);          // ETOT
    int* off       = pairs + ETOT;               // M2
    int* bsum2     = off + M2;                   // 2048
    int* boff2     = bsum2 + 2048;               // 2048
    float4* nrec1  = (float4*)(boff2 + 2048);    // N*16B: {x0,x1,as1,pad}

    // ---- CSR build + fused precompute (6 launches) ----
    chunk_hist<<<NCHUNK, 1024, 0, stream>>>(ei, H);
    cscan_local_prep<<<NSB2 + 1, 512, 0, stream>>>(H, off, bsum2,
                                                   W1, as1w, ad1w, W2, as2w, ad2w, cvec);
    cscan_bsum_alpha1<<<1 + (NNODES + 1023) / 1024, 1024, 0, stream>>>(
        bsum2, boff2, x, cvec, nrec1, adb);
    chunk_scatter<<<NCHUNK, 1024, 0, stream>>>(ei, off, boff2, H, pairs);

    // ---- fused fine sort + layer-1 aggregation (overwrites H slot as nrec2) ----
    fine_agg1<<<NBUCK, 512, 0, stream>>>(off, boff2, pairs, nrec1, adb, W1, b1,
                                         cvec, row_start, csr_src, nrec2, ad2b);

    // ---- Layer 2: aggregate packed records, W2 in epilogue ----
    agg_l2<<<NNODES / 16, 256, 0, stream>>>(row_start, csr_src, nrec2, ad2b, W2, b2, out);
}

// Round 20
// 197.523 us; speedup vs baseline: 1.0121x; 1.0121x over previous
//
#include <hip/hip_runtime.h>

#define NNODES 100000
#define NEDGES 3200000
#define ETOT   (NEDGES + NNODES)
#define NEG_SLOPE 0.2f
#define LOG2E 1.4426950408889634f

#define NPB 64                               // nodes per bucket (dst >> 6)
#define NBUCK ((NNODES + NPB - 1) / NPB)     // 1563 buckets
#define NCHUNK 256                           // edge chunks (proven 256 geometry)
#define CHUNK_E ((ETOT + NCHUNK - 1) / NCHUNK)  // 12891 edges/chunk
#define M2 (NBUCK * NCHUNK)                  // 400128 (chunk-scan length)
#define NSB2 ((M2 + 511) / 512)              // 782
#define FS_CAP 4096                          // fine_agg1 LDS staging capacity

// bf16 storage via raw ushort — no hip_fp16.h / hip_bf16.h dependency.
__device__ __forceinline__ unsigned short f2bf(float f) {
    unsigned u = __float_as_uint(f);
    u += 0x7FFFu + ((u >> 16) & 1u);         // round-to-nearest-even
    return (unsigned short)(u >> 16);
}

// edge e in [0, NEDGES): src = ei[e], dst = ei[NEDGES+e]
// edge e in [NEDGES, ETOT): self-loop, src = dst = e - NEDGES
__device__ __forceinline__ void edge_sd(int e, const int* __restrict__ ei, int& s, int& d) {
    if (e < NEDGES) { s = ei[e]; d = ei[NEDGES + e]; }
    else            { s = e - NEDGES; d = s; }
}

__device__ __forceinline__ float lrelu(float v) {
    return v > 0.0f ? v : NEG_SLOPE * v;
}

// Alpha tables pre-scaled by log2(e) (round-26): edge weight = single v_exp_f32.
__device__ __forceinline__ float edge_w(float z) {
    return __builtin_amdgcn_exp2f(lrelu(z));
}

// ---- cross-lane primitives ----
template<int CTRL>
__device__ __forceinline__ float dpp_mov(float v) {
    return __int_as_float(__builtin_amdgcn_mov_dpp(__float_as_int(v), CTRL, 0xF, 0xF, true));
}
template<int CTRL>
__device__ __forceinline__ float dpp_add(float v) { return v + dpp_mov<CTRL>(v); }
template<int IMM>
__device__ __forceinline__ float swz(float v) {
    return __int_as_float(__builtin_amdgcn_ds_swizzle(__float_as_int(v), IMM));
}
// Sum over all 16 lanes of each row (rotations 1,2,4,8).
__device__ __forceinline__ float row16_sum(float v) {
    v = dpp_add<0x121>(v);   // row_ror:1
    v = dpp_add<0x122>(v);   // row_ror:2
    v = dpp_add<0x124>(v);   // row_ror:4
    v = dpp_add<0x128>(v);   // row_ror:8
    return v;
}
// Wave-internal inclusive scan (6 shfl_up stages, no barriers).
__device__ __forceinline__ int wave_iscan(int v, int lane) {
#pragma unroll
    for (int o = 1; o <= 32; o <<= 1) {
        int u = __shfl_up(v, o);
        if (lane >= o) v += u;
    }
    return v;
}

// ---------------- deterministic chunked bucket sort ----------------

__global__ void chunk_hist(const int* __restrict__ ei, int* __restrict__ H) {
    __shared__ int h[NBUCK];
    int c = blockIdx.x;
    for (int i = threadIdx.x; i < NBUCK; i += blockDim.x) h[i] = 0;
    __syncthreads();
    int lo = c * CHUNK_E, hi = lo + CHUNK_E; if (hi > ETOT) hi = ETOT;
    for (int e = lo + threadIdx.x; e < hi; e += blockDim.x) {
        int d = (e < NEDGES) ? ei[NEDGES + e] : (e - NEDGES);
        atomicAdd(&h[d >> 6], 1);
    }
    __syncthreads();
    for (int i = threadIdx.x; i < NBUCK; i += blockDim.x) H[c * NBUCK + i] = h[i];
}

// 3-phase scan, local stage. Round-37: Hillis-Steele (18 barriers) replaced by
// per-wave shfl_up scans + one wave-totals combine (1 barrier). Same algebra:
// off[i] = incl - orig (exclusive within the 512-block); bsum2 = block total.
// prep merged in (block NSB2). cvec: [0,1]=c1s [2,3]=c1d [4..19]=c2s
// [20..35]=c2d (log2e-prescaled).
__global__ __launch_bounds__(512)
void cscan_local_prep(const int* __restrict__ H, int* __restrict__ off,
                      int* __restrict__ bsum2,
                      const float* __restrict__ W1, const float* __restrict__ as1,
                      const float* __restrict__ ad1, const float* __restrict__ W2,
                      const float* __restrict__ as2, const float* __restrict__ ad2,
                      float* __restrict__ cvec) {
    int blk = blockIdx.x, t = threadIdx.x;
    if (blk == NSB2) {                       // prep role
        if (t < 2) {
            float s = 0.f, d = 0.f;
            for (int f = 0; f < 16; ++f) { s += W1[t * 16 + f] * as1[f]; d += W1[t * 16 + f] * ad1[f]; }
            cvec[t] = s * LOG2E; cvec[2 + t] = d * LOG2E;
        }
        if (t < 16) {
            float s = 0.f, d = 0.f;
            for (int f = 0; f < 64; ++f) { s += W2[t * 64 + f] * as2[f]; d += W2[t * 64 + f] * ad2[f]; }
            cvec[4 + t] = s * LOG2E; cvec[20 + t] = d * LOG2E;
        }
        return;
    }
    __shared__ int wt[8];
    int lane = t & 63, wid = t >> 6;
    int i = blk * 512 + t;
    int orig = (i < M2) ? H[(i & (NCHUNK - 1)) * NBUCK + (i >> 8)] : 0;
    int v = wave_iscan(orig, lane);
    if (lane == 63) wt[wid] = v;
    __syncthreads();
    int pre = 0;
#pragma unroll
    for (int w = 0; w < 8; ++w) pre += (w < wid) ? wt[w] : 0;
    v += pre;
    if (i < M2) off[i] = v - orig;
    if (t == 511) bsum2[blk] = v;
}

// bsum scan (block 0) + alpha1 node records (blocks 1..). Layer-1 record
// (16B, one line per edge gather): {x0, x1, as1, pad}.
__global__ __launch_bounds__(1024)
void cscan_bsum_alpha1(const int* __restrict__ bsum2, int* __restrict__ boff2,
                       const float* __restrict__ x, const float* __restrict__ cvec,
                       float4* __restrict__ nrec1, float* __restrict__ ad_) {
    int t = threadIdx.x;
    if (blockIdx.x == 0) {
        __shared__ int arr[1024];
        int v = (t < NSB2) ? bsum2[t] : 0;
        arr[t] = v;
        __syncthreads();
        for (int o = 1; o < 1024; o <<= 1) {
            int u = (t >= o) ? arr[t - o] : 0;
            __syncthreads();
            arr[t] += u;
            __syncthreads();
        }
        if (t < NSB2) boff2[t] = arr[t] - v;
        return;
    }
    int n = (blockIdx.x - 1) * 1024 + t;
    if (n >= NNODES) return;
    float2 xv = ((const float2*)x)[n];
    float as = xv.x * cvec[0] + xv.y * cvec[1];
    ad_[n] = xv.x * cvec[2] + xv.y * cvec[3];
    nrec1[n] = make_float4(xv.x, xv.y, as, 0.f);
}

// LDS-staged scatter (round-22, proven). Round-37: the 2048-wide LDS scan
// (22 barriers, 8KB sc[]) replaced by 2-registers/thread per-wave shfl scans
// + one 32-entry wave-totals combine (1 barrier). excl = incl - orig.
__global__ __launch_bounds__(1024)
void chunk_scatter(const int* __restrict__ ei, const int* __restrict__ off,
                   const int* __restrict__ boff2, const int* __restrict__ H,
                   int* __restrict__ pairs) {
    __shared__ int plds[CHUNK_E];            // 51564 B: packed pair per local slot
    __shared__ unsigned short blds[CHUNK_E]; // 25782 B: bucket id per local slot
    __shared__ int lcur[NBUCK];              //  6252 B: local alloc cursor
    __shared__ int gbase[NBUCK];             //  6252 B: off_g[b,c] - lpref[b]
    __shared__ int wt0[16], wt1[16];
    int c = blockIdx.x, t = threadIdx.x;
    int lane = t & 63, wid = t >> 6;
    int b1i = t + 1024;
    int orig0 = (t < NBUCK) ? H[c * NBUCK + t] : 0;
    int orig1 = (b1i < NBUCK) ? H[c * NBUCK + b1i] : 0;
    int v0 = wave_iscan(orig0, lane);
    int v1 = wave_iscan(orig1, lane);
    if (lane == 63) { wt0[wid] = v0; wt1[wid] = v1; }
    __syncthreads();
    int pre0 = 0, tot0 = 0, pre1 = 0;
#pragma unroll
    for (int w = 0; w < 16; ++w) {
        tot0 += wt0[w];
        pre0 += (w < wid) ? wt0[w] : 0;
        pre1 += (w < wid) ? wt1[w] : 0;
    }
    v0 += pre0;
    v1 += tot0 + pre1;
    if (t < NBUCK) {
        int excl = v0 - orig0;
        lcur[t]  = excl;
        gbase[t] = off[t * NCHUNK + c] + boff2[t >> 1] - excl;
    }
    if (b1i < NBUCK) {
        int excl = v1 - orig1;
        lcur[b1i]  = excl;
        gbase[b1i] = off[b1i * NCHUNK + c] + boff2[b1i >> 1] - excl;
    }
    __syncthreads();
    int lo = c * CHUNK_E, hi = lo + CHUNK_E; if (hi > ETOT) hi = ETOT;
    int n = hi - lo;
    for (int e = lo + t; e < hi; e += 1024) {
        int s, d; edge_sd(e, ei, s, d);
        int b = d >> 6;
        int slot = atomicAdd(&lcur[b], 1);
        plds[slot] = ((d & 63) << 17) | s;          // src < 2^17
        blds[slot] = (unsigned short)b;
    }
    __syncthreads();
    for (int i = t; i < n; i += 1024)
        pairs[gbase[blds[i]] + i] = plds[i];        // coalesced within segments
}

// ---------------- fused fine sort + layer-1 aggregation -----------------------
// Round-30 fusion; round-34 16-lane groups. Round-37: the NPB=64 node-degree
// scan fits one wave — shfl_up scan in wave 0, zero interior barriers (was 12).
__global__ __launch_bounds__(512)
void fine_agg1(const int* __restrict__ off, const int* __restrict__ boff2,
               const int* __restrict__ pairs,
               const float4* __restrict__ nrec1, const float* __restrict__ ad_,
               const float* __restrict__ W1, const float* __restrict__ b1,
               const float* __restrict__ cvec,
               int* __restrict__ row_start, int* __restrict__ csr_src,
               float* __restrict__ nrec2, float* __restrict__ ad2_) {
    __shared__ int sp[FS_CAP];               // 16KB arrival-order pairs
    __shared__ int spc[FS_CAP];              // 16KB node-compacted src ids
    __shared__ int arr[NPB];
    __shared__ int cur[NPB];
    __shared__ int lstart[NPB + 1];
    int b = blockIdx.x;
    int t = threadIdx.x;
    int base = off[b * NCHUNK] + boff2[b >> 1];
    int bend = (b == NBUCK - 1) ? ETOT : off[(b + 1) * NCHUNK] + boff2[(b + 1) >> 1];
    int n = bend - base;
    if (t < NPB) arr[t] = 0;
    __syncthreads();
    bool fits = (n <= FS_CAP);
    if (fits) {
        for (int i = t; i < n; i += 512) {
            int p = pairs[base + i];
            sp[i] = p;
            atomicAdd(&arr[p >> 17], 1);
        }
    } else {
        for (int i = t; i < n; i += 512)
            atomicAdd(&arr[pairs[base + i] >> 17], 1);
    }
    __syncthreads();
    if (t < NPB) {                               // one wave: scan + outputs
        int orig = arr[t];
        int incl = wave_iscan(orig, t);          // lanes 0..63 of wave 0
        int node = b * NPB + t;
        int start = base + incl - orig;          // exclusive prefix
        cur[t] = start;
        lstart[t] = start;
        if (node < NNODES) row_start[node] = start;
    }
    if (t == 0) lstart[NPB] = bend;
    if (b == NBUCK - 1 && t == 0) row_start[NNODES] = ETOT;
    __syncthreads();
    if (fits) {
        for (int i = t; i < n; i += 512) {
            int p = sp[i];
            int slot = atomicAdd(&cur[p >> 17], 1);
            int src = p & 0x1FFFF;
            csr_src[slot] = src;
            spc[slot - base] = src;               // LDS copy for fused agg
        }
    } else {
        for (int i = t; i < n; i += 512) {
            int p = pairs[base + i];
            int slot = atomicAdd(&cur[p >> 17], 1);
            csr_src[slot] = p & 0x1FFFF;
        }
        __threadfence_block();
    }
    __syncthreads();
    // ---- fused agg_l1: 8 waves x 4 quads = 32 nodes per pass, 2 passes ----
    int wave = t >> 6;
    int quad = (t >> 4) & 3;
    int l16  = t & 15;
#pragma unroll
    for (int pass = 0; pass < 2; ++pass) {
        int ln = pass * 32 + wave * 4 + quad;     // 0..63, uniform per 16-lane group
        int node = b * NPB + ln;
        if (node >= NNODES) continue;             // uniform branch per group
        int nbase = lstart[ln], nend = lstart[ln + 1];
        float adv = ad_[node];
        float a0 = 0.f, a1 = 0.f, ss = 0.f;
        if (fits) {
            for (int i = nbase + l16; i < nend; i += 16) {
                int sj = spc[i - base];
                float4 r = nrec1[sj];             // ONE 16B gather: x0,x1,as1
                float w = edge_w(r.z + adv);
                ss += w; a0 += w * r.x; a1 += w * r.y;
            }
        } else {
            for (int i = nbase + l16; i < nend; i += 16) {
                int sj = csr_src[i];
                float4 r = nrec1[sj];
                float w = edge_w(r.z + adv);
                ss += w; a0 += w * r.x; a1 += w * r.y;
            }
        }
        a0 = row16_sum(a0); a1 = row16_sum(a1); ss = row16_sum(ss);
        int f = l16;                              // each lane owns one feature
        float vv = (a0 * W1[f] + a1 * W1[16 + f]) / ss + b1[f];
        float vr = vv > 0.f ? vv : 0.f;
        unsigned short* grow = (unsigned short*)(nrec2 + (size_t)node * 16);
        grow[l16] = f2bf(vr);                     // bf16 g row, bytes 0..31
        // fused alpha2 (f32): row-local 16-feature sums
        float s2 = vr * cvec[4 + f];
        float d2 = vr * cvec[20 + f];
        s2 = row16_sum(s2); d2 = row16_sum(d2);
        if (l16 == 0) {
            nrec2[(size_t)node * 16 + 8] = s2;    // as2 at bytes 32..35 (same line)
            ad2_[node] = d2;
        }
    }
}

// ---------------- layer 2: aggregate bf16 g, @W2 in epilogue ------------------
// Four nodes per wave, 16 lanes each (round-34); one 64B record line per edge
// (round-27); transposed butterfly completes within the 16-lane row.
__global__ void agg_l2(const int* __restrict__ row_start, const int* __restrict__ csr_src,
                       const float* __restrict__ nrec2, const float* __restrict__ ad_,
                       const float* __restrict__ W2, const float* __restrict__ b2,
                       float* __restrict__ out) {
    __shared__ float tot[4][4][16];
    int wave = threadIdx.x >> 6;
    int quad = (threadIdx.x >> 4) & 3;
    int l16  = threadIdx.x & 15;
    int node = blockIdx.x * 16 + wave * 4 + quad;  // exact grid: NNODES/16 blocks
    int base = row_start[node], end = row_start[node + 1];
    float adv = ad_[node];
    float acc[16];
#pragma unroll
    for (int k = 0; k < 16; ++k) acc[k] = 0.f;
    float ss = 0.f;
    for (int i = base + l16; i < end; i += 16) {
        int sj = csr_src[i];                        // coalesced within group
        const float* recf = nrec2 + (size_t)sj * 16;
        const uint4* rec4 = (const uint4*)recf;
        uint4 u0 = rec4[0], u1 = rec4[1];           // g row bf16x16 (32B)
        float as2v = recf[8];                       // as2 (same 64B line)
        float w = edge_w(as2v + adv);
        ss += w;
        unsigned uu[8] = {u0.x, u0.y, u0.z, u0.w, u1.x, u1.y, u1.z, u1.w};
#pragma unroll
        for (int j = 0; j < 8; ++j) {
            acc[2 * j]     += w * __uint_as_float(uu[j] << 16);
            acc[2 * j + 1] += w * __uint_as_float(uu[j] & 0xFFFF0000u);
        }
    }
    // ---- transposed butterfly within the 16-lane row: lane l16 -> feature l16
#pragma unroll
    for (int j = 0; j < 8; ++j) {
        float keep = (l16 & 1) ? acc[2 * j + 1] : acc[2 * j];
        float send = (l16 & 1) ? acc[2 * j]     : acc[2 * j + 1];
        acc[j] = keep + dpp_mov<0xB1>(send);
    }
#pragma unroll
    for (int j = 0; j < 4; ++j) {
        float keep = (l16 & 2) ? acc[2 * j + 1] : acc[2 * j];
        float send = (l16 & 2) ? acc[2 * j]     : acc[2 * j + 1];
        acc[j] = keep + dpp_mov<0x4E>(send);
    }
#pragma unroll
    for (int j = 0; j < 2; ++j) {
        float keep = (l16 & 4) ? acc[2 * j + 1] : acc[2 * j];
        float send = (l16 & 4) ? acc[2 * j]     : acc[2 * j + 1];
        acc[j] = keep + swz<0x101F>(send);
    }
    float r;
    {
        float keep = (l16 & 8) ? acc[1] : acc[0];
        float send = (l16 & 8) ? acc[0] : acc[1];
        r = keep + swz<0x201F>(send);
    }
    // r is the complete per-node total of feature l16 (no swz16 needed).
    float st = row16_sum(ss);
    tot[wave][quad][l16] = r;                      // in-order wave-local LDS
    float inv = 1.0f / st;
#pragma unroll
    for (int j = 0; j < 4; ++j) {
        float o = 0.f;
#pragma unroll
        for (int k = 0; k < 16; ++k)
            o += tot[wave][quad][k] * W2[k * 64 + j * 16 + l16];  // 64B/group
        o = o * inv + b2[j * 16 + l16];
        float rv = o > 0.f ? o : 0.f;
        out[(size_t)node * 64 + j * 16 + l16] = rv;
    }
}

extern "C" void kernel_launch(void* const* d_in, const int* in_sizes, int n_in,
                              void* d_out, int out_size, void* d_ws, size_t ws_size,
                              hipStream_t stream) {
    const float* x     = (const float*)d_in[0];
    const int*   ei    = (const int*)  d_in[1];
    const float* W1    = (const float*)d_in[2];
    const float* as1w  = (const float*)d_in[3];
    const float* ad1w  = (const float*)d_in[4];
    const float* b1    = (const float*)d_in[5];
    const float* W2    = (const float*)d_in[6];
    const float* as2w  = (const float*)d_in[7];
    const float* ad2w  = (const float*)d_in[8];
    const float* b2    = (const float*)d_in[9];
    float* out = (float*)d_out;

    // ws layout (4-byte elems, ~38.8 MB; 40.4 MB proven available):
    //   row_start[N+4] | csr_src[ETOT] | nrec2[N*16 f32 slots = 64B/node] |
    //   adb[N] | ad2b[N] | cvec[64] | pairs[ETOT] | H[M2] | off[M2] |
    //   bsum2[1024] | boff2[1024] | nrec1[N float4]
    int* row_start = (int*)d_ws;
    int* csr_src   = row_start + (NNODES + 4);
    float* nrec2   = (float*)(csr_src + ETOT);   // N*64B: g bf16[16] + as2 + pad
    float* adb     = nrec2 + (size_t)NNODES * 16;
    float* ad2b    = adb + NNODES;
    float* cvec    = ad2b + NNODES;              // 36 floats used
    int* pairs     = (int*)(cvec + 64);          // ETOT
    int* H         = pairs + ETOT;               // M2
    int* off       = H + M2;                     // M2
    int* bsum2     = off + M2;                   // 1024
    int* boff2     = bsum2 + 1024;               // 1024
    float4* nrec1  = (float4*)(boff2 + 1024);    // N*16B: {x0,x1,as1,pad}

    // ---- CSR build + fused precompute (6 launches) ----
    chunk_hist<<<NCHUNK, 1024, 0, stream>>>(ei, H);
    cscan_local_prep<<<NSB2 + 1, 512, 0, stream>>>(H, off, bsum2,
                                                   W1, as1w, ad1w, W2, as2w, ad2w, cvec);
    cscan_bsum_alpha1<<<1 + (NNODES + 1023) / 1024, 1024, 0, stream>>>(
        bsum2, boff2, x, cvec, nrec1, adb);
    chunk_scatter<<<NCHUNK, 1024, 0, stream>>>(ei, off, boff2, H, pairs);

    // ---- fused fine sort + layer-1 aggregation ----
    fine_agg1<<<NBUCK, 512, 0, stream>>>(off, boff2, pairs, nrec1, adb, W1, b1,
                                         cvec, row_start, csr_src, nrec2, ad2b);

    // ---- Layer 2: aggregate packed records, W2 in epilogue ----
    agg_l2<<<NNODES / 16, 256, 0, stream>>>(row_start, csr_src, nrec2, ad2b, W2, b2, out);
}